// Round 10
// baseline (210.297 us; speedup 1.0000x reference)
//
#include <hip/hip_runtime.h>
#include <cstdint>
#include <cstddef>

// [B,H,N,Dh] = [4,16,2048,64]; out[b,h,m,d] = (sum_n softmax(QK^T)[n,m]) * v[b,h,m,d]
#define B_    4
#define H_    16
#define N_    2048
#define D_    64
#define BH_   (B_*H_)
#define SCALE 0.125f
#define QSCL  0.18033688011f      // SCALE * log2(e)

#define NT    16                  // streamed tiles (128 rows each)
#define TILEB 16384               // bytes per bf16 tile: 128 rows x 128 B
#define BHB   (NT*TILEB)          // 256 KB per (bh, tensor)

typedef __attribute__((ext_vector_type(8))) short bf16x8;
typedef __attribute__((ext_vector_type(4))) float f32x4;

#if __has_builtin(__builtin_amdgcn_exp2f)
#define EXP2(x) __builtin_amdgcn_exp2f(x)
#else
#define EXP2(x) exp2f(x)
#endif

__device__ __forceinline__ short f2bf(float f) {
    union { float f; unsigned u; } x; x.f = f;
    unsigned r = x.u + 0x7FFF + ((x.u >> 16) & 1);  // RNE
    return (short)(r >> 16);
}

// Fragment-major byte offset of chunk (row, cc) inside a (bh, tensor) panel:
// tile(128 rows) -> group g=(row>>4)&7 (16 rows, 2 KB) -> frag f=cc>>2 (1 KB)
// -> lane l = (cc&3)*16 + (row&15) at l*16. A wave's b-frag load for group g,
// frag f is then ONE coalesced 1 KB read at base + g*2048 + f*1024 + l*16.
__device__ __forceinline__ size_t fmaj(int row, int cc) {
    return ((size_t)(row >> 7) * TILEB) + (((row >> 4) & 7) << 11)
         + ((cc >> 2) << 10) + ((cc & 3) << 8) + ((row & 15) << 4);
}

// ---------------------------------------------------------------------------
// Pre-pass: qk[] = [ Q' (bf16, x QSCL) | K' (bf16) ], fragment-major layout
// ---------------------------------------------------------------------------
__global__ __launch_bounds__(512)
void mha_convert(const float* __restrict__ q, const float* __restrict__ k,
                 char* __restrict__ qk)
{
    const int gid = blockIdx.x * 512 + threadIdx.x;     // 2*64*16384 chunks
    const int half = BH_ * N_ * 8;
    const bool isq = gid < half;
    const float* src = isq ? q : k;
    const float scl = isq ? QSCL : 1.0f;
    char* dst = qk + (isq ? 0 : (size_t)BH_ * BHB);
    const int id = isq ? gid : gid - half;
    const int bh  = id >> 14;            // 16384 chunks per bh
    const int row = (id >> 3) & 2047;
    const int cc  = id & 7;
    const float* p = src + ((size_t)bh * N_ + row) * D_ + cc * 8;
    float4 a = *(const float4*)p;
    float4 b = *(const float4*)(p + 4);
    bf16x8 o;
    o[0] = f2bf(a.x * scl); o[1] = f2bf(a.y * scl);
    o[2] = f2bf(a.z * scl); o[3] = f2bf(a.w * scl);
    o[4] = f2bf(b.x * scl); o[5] = f2bf(b.y * scl);
    o[6] = f2bf(b.z * scl); o[7] = f2bf(b.w * scl);
    *(bf16x8*)(dst + (size_t)bh * BHB + fmaj(row, cc)) = o;
}

// ---------------------------------------------------------------------------
// Pass 1: rinv[bh,n] = 1 / sum_m 2^(q'_n . k'_m)
// wg = (bh, 256-row panel), 4 waves x 64 fixed rows in registers.
// K' streamed DIRECTLY from global/L2 (no LDS, no barriers).
// ---------------------------------------------------------------------------
__global__ __launch_bounds__(256)
void mha_rowsum5(const char* __restrict__ qk, float* __restrict__ rinv)
{
    const int t = threadIdx.x, w = t >> 6, l = t & 63;
    const int wid = (blockIdx.x & 7) * 64 + (blockIdx.x >> 3);  // XCD swizzle (512 wgs)
    const int bh = wid >> 3, rb = wid & 7;

    const char* Qp = qk + (size_t)bh * BHB;
    const char* Kp = qk + (size_t)BH_ * BHB + (size_t)bh * BHB;
    const int rbase = rb * 256 + w * 64;

    // Fixed A frags: rows rbase + rg*16 + (l&15), k-chunks kh*4+(l>>4)
    bf16x8 af[4][2];
    #pragma unroll
    for (int rg = 0; rg < 4; ++rg) {
        const int row0 = rbase + rg * 16;
        const char* gb = Qp + (row0 >> 7) * TILEB + (((row0 >> 4) & 7) << 11);
        af[rg][0] = *(const bf16x8*)(gb + l * 16);
        af[rg][1] = *(const bf16x8*)(gb + 1024 + l * 16);
    }

    float rs[4][4] = {};

    #pragma unroll 1
    for (int ct = 0; ct < NT; ++ct) {
        const char* tb = Kp + (size_t)ct * TILEB;
        #pragma unroll
        for (int g = 0; g < 8; ++g) {
            bf16x8 b0 = *(const bf16x8*)(tb + g * 2048 + l * 16);
            bf16x8 b1 = *(const bf16x8*)(tb + g * 2048 + 1024 + l * 16);
            #pragma unroll
            for (int rg = 0; rg < 4; ++rg) {
                f32x4 c = {0.f, 0.f, 0.f, 0.f};
                c = __builtin_amdgcn_mfma_f32_16x16x32_bf16(af[rg][0], b0, c, 0, 0, 0);
                c = __builtin_amdgcn_mfma_f32_16x16x32_bf16(af[rg][1], b1, c, 0, 0, 0);
                rs[rg][0] += EXP2(c[0]);
                rs[rg][1] += EXP2(c[1]);
                rs[rg][2] += EXP2(c[2]);
                rs[rg][3] += EXP2(c[3]);
            }
        }
    }

    // Reduce across the 16 col-lanes (l&15); S-row = rg*16 + (l>>4)*4 + i.
    #pragma unroll
    for (int rg = 0; rg < 4; ++rg)
        #pragma unroll
        for (int i = 0; i < 4; ++i) {
            rs[rg][i] += __shfl_xor(rs[rg][i], 1);
            rs[rg][i] += __shfl_xor(rs[rg][i], 2);
            rs[rg][i] += __shfl_xor(rs[rg][i], 4);
            rs[rg][i] += __shfl_xor(rs[rg][i], 8);
        }
    if ((l & 15) == 0) {
        #pragma unroll
        for (int rg = 0; rg < 4; ++rg) {
            const int rr = rbase + rg * 16 + (l >> 4) * 4;
            #pragma unroll
            for (int i = 0; i < 4; ++i)
                rinv[(size_t)bh * N_ + rr + i] = 1.0f / rs[rg][i];
        }
    }
}

// ---------------------------------------------------------------------------
// Pass 2: colsum[m] = sum_n 2^(q'_n . k'_m) * rinv[n]; out = colsum[m]*v[m,:]
// wg = (bh, 256-col panel), 4 waves x 64 fixed cols; Q' streamed from L2.
// ---------------------------------------------------------------------------
__global__ __launch_bounds__(256)
void mha_colsum5(const char* __restrict__ qk, const float* __restrict__ rinv,
                 const float* __restrict__ v, float* __restrict__ out)
{
    __shared__ float cs[256];

    const int t = threadIdx.x, w = t >> 6, l = t & 63;
    const int wid = (blockIdx.x & 7) * 64 + (blockIdx.x >> 3);
    const int bh = wid >> 3, cb = wid & 7;

    const char* Qp = qk + (size_t)bh * BHB;
    const char* Kp = qk + (size_t)BH_ * BHB + (size_t)bh * BHB;
    const float* Rg = rinv + (size_t)bh * N_;
    const int cbase = cb * 256 + w * 64;

    // Fixed B frags: cols cbase + rg*16 + (l&15)
    bf16x8 kf[4][2];
    #pragma unroll
    for (int rg = 0; rg < 4; ++rg) {
        const int col0 = cbase + rg * 16;
        const char* gb = Kp + (col0 >> 7) * TILEB + (((col0 >> 4) & 7) << 11);
        kf[rg][0] = *(const bf16x8*)(gb + l * 16);
        kf[rg][1] = *(const bf16x8*)(gb + 1024 + l * 16);
    }

    float ca[4] = {0.f, 0.f, 0.f, 0.f};

    #pragma unroll 1
    for (int rt = 0; rt < NT; ++rt) {
        const char* tb = Qp + (size_t)rt * TILEB;
        #pragma unroll
        for (int g = 0; g < 8; ++g) {
            bf16x8 a0 = *(const bf16x8*)(tb + g * 2048 + l * 16);
            bf16x8 a1 = *(const bf16x8*)(tb + g * 2048 + 1024 + l * 16);
            float4 r4 = *(const float4*)(Rg + rt * 128 + g * 16 + (l >> 4) * 4);
            #pragma unroll
            for (int rg = 0; rg < 4; ++rg) {
                f32x4 c = {0.f, 0.f, 0.f, 0.f};
                c = __builtin_amdgcn_mfma_f32_16x16x32_bf16(a0, kf[rg][0], c, 0, 0, 0);
                c = __builtin_amdgcn_mfma_f32_16x16x32_bf16(a1, kf[rg][1], c, 0, 0, 0);
                ca[rg] += EXP2(c[0]) * r4.x + EXP2(c[1]) * r4.y
                        + EXP2(c[2]) * r4.z + EXP2(c[3]) * r4.w;
            }
        }
    }

    // Reduce across the 4 row-quarters; lanes 0..15 hold colsum of col rg*16+l
    #pragma unroll
    for (int rg = 0; rg < 4; ++rg) {
        ca[rg] += __shfl_xor(ca[rg], 16);
        ca[rg] += __shfl_xor(ca[rg], 32);
        if (l < 16) cs[w * 64 + rg * 16 + l] = ca[rg];
    }
    __syncthreads();

    // out[m][d] = colsum[m] * v[m][d]  (256 rows x 64 d, float4-vectorized)
    const float4* Vg = (const float4*)(v + ((size_t)bh * N_ + cb * 256) * D_);
    float4* Og = (float4*)(out + ((size_t)bh * N_ + cb * 256) * D_);
    #pragma unroll
    for (int i = 0; i < 16; ++i) {
        int id = i * 256 + t;                // 4096 float4 units
        float s = cs[id >> 4];
        float4 vv = Vg[id];
        float4 o; o.x = vv.x * s; o.y = vv.y * s; o.z = vv.z * s; o.w = vv.w * s;
        Og[id] = o;
    }
}

// ===========================================================================
// Fallback (R2 path) if ws_size is too small for the bf16 staging buffers.
// ===========================================================================
#define FTS 128
#define FNT 16

__device__ __forceinline__ bf16x8 cvt8(const float* p) {
    float4 a = *(const float4*)p;
    float4 b = *(const float4*)(p + 4);
    bf16x8 r;
    r[0] = f2bf(a.x); r[1] = f2bf(a.y); r[2] = f2bf(a.z); r[3] = f2bf(a.w);
    r[4] = f2bf(b.x); r[5] = f2bf(b.y); r[6] = f2bf(b.z); r[7] = f2bf(b.w);
    return r;
}
__device__ __forceinline__ void fstage(char* lds, const float* src, int t) {
    #pragma unroll
    for (int i = 0; i < 2; ++i) {
        int ch = i * 512 + t, r = ch >> 3, cc = ch & 7;
        bf16x8 v = cvt8(src + (size_t)r * D_ + cc * 8);
        *(bf16x8*)(lds + r * 128 + ((cc ^ (r & 7)) << 4)) = v;
    }
}
__device__ __forceinline__ bf16x8 fread(const char* lds, int row, int cc) {
    return *(const bf16x8*)(lds + row * 128 + ((cc ^ (row & 7)) << 4));
}

__global__ __launch_bounds__(512)
void mha_rowsum_fb(const float* __restrict__ q, const float* __restrict__ k,
                   float* __restrict__ rinv)
{
    __shared__ __align__(16) char KT[FTS * 128];
    const int t = threadIdx.x, w = t >> 6, l = t & 63;
    const int bh = blockIdx.x / FNT, rb = blockIdx.x % FNT;
    const float* Qg = q + (size_t)bh * N_ * D_;
    const float* Kg = k + (size_t)bh * N_ * D_;
    const int qrow = rb * FTS + w * 16 + (l & 15);
    bf16x8 af[2];
    #pragma unroll
    for (int kh = 0; kh < 2; ++kh)
        af[kh] = cvt8(Qg + (size_t)qrow * D_ + kh * 32 + (l >> 4) * 8);
    float rs[4] = {0.f, 0.f, 0.f, 0.f};
    for (int ct = 0; ct < FNT; ++ct) {
        __syncthreads();
        fstage(KT, Kg + (size_t)ct * FTS * D_, t);
        __syncthreads();
        #pragma unroll
        for (int cj = 0; cj < 8; ++cj) {
            const int krow = cj * 16 + (l & 15);
            f32x4 c = {0.f, 0.f, 0.f, 0.f};
            #pragma unroll
            for (int kh = 0; kh < 2; ++kh)
                c = __builtin_amdgcn_mfma_f32_16x16x32_bf16(af[kh], fread(KT, krow, kh * 4 + (l >> 4)), c, 0, 0, 0);
            rs[0] += __expf(c[0] * SCALE); rs[1] += __expf(c[1] * SCALE);
            rs[2] += __expf(c[2] * SCALE); rs[3] += __expf(c[3] * SCALE);
        }
    }
    #pragma unroll
    for (int i = 0; i < 4; ++i) {
        rs[i] += __shfl_xor(rs[i], 1); rs[i] += __shfl_xor(rs[i], 2);
        rs[i] += __shfl_xor(rs[i], 4); rs[i] += __shfl_xor(rs[i], 8);
    }
    if ((l & 15) == 0) {
        const int rbase = rb * FTS + w * 16 + (l >> 4) * 4;
        #pragma unroll
        for (int i = 0; i < 4; ++i)
            rinv[(size_t)bh * N_ + rbase + i] = 1.0f / rs[i];
    }
}

__global__ __launch_bounds__(512)
void mha_colsum_fb(const float* __restrict__ q, const float* __restrict__ k,
                   const float* __restrict__ v, const float* __restrict__ rinv,
                   float* __restrict__ out)
{
    __shared__ __align__(16) char QT[FTS * 128];
    __shared__ float rv[FTS];
    __shared__ float cs[FTS];
    const int t = threadIdx.x, w = t >> 6, l = t & 63;
    const int bh = blockIdx.x / FNT, cb = blockIdx.x % FNT;
    const float* Qg = q + (size_t)bh * N_ * D_;
    const float* Kg = k + (size_t)bh * N_ * D_;
    const float* Rg = rinv + (size_t)bh * N_;
    const int kcol = cb * FTS + w * 16 + (l & 15);
    bf16x8 kf[2];
    #pragma unroll
    for (int kh = 0; kh < 2; ++kh)
        kf[kh] = cvt8(Kg + (size_t)kcol * D_ + kh * 32 + (l >> 4) * 8);
    float ca = 0.f;
    for (int rt = 0; rt < FNT; ++rt) {
        __syncthreads();
        fstage(QT, Qg + (size_t)rt * FTS * D_, t);
        if (t < FTS) rv[t] = Rg[rt * FTS + t];
        __syncthreads();
        #pragma unroll
        for (int rj = 0; rj < 8; ++rj) {
            const int qr = rj * 16 + (l & 15);
            f32x4 c = {0.f, 0.f, 0.f, 0.f};
            #pragma unroll
            for (int kh = 0; kh < 2; ++kh)
                c = __builtin_amdgcn_mfma_f32_16x16x32_bf16(fread(QT, qr, kh * 4 + (l >> 4)), kf[kh], c, 0, 0, 0);
            float4 r4 = *(const float4*)&rv[rj * 16 + (l >> 4) * 4];
            ca += __expf(c[0] * SCALE) * r4.x + __expf(c[1] * SCALE) * r4.y
                + __expf(c[2] * SCALE) * r4.z + __expf(c[3] * SCALE) * r4.w;
        }
    }
    ca += __shfl_xor(ca, 16); ca += __shfl_xor(ca, 32);
    if (l < 16) cs[w * 16 + l] = ca;
    __syncthreads();
    const float4* Vg = (const float4*)(v + (size_t)bh * N_ * D_ + (size_t)cb * FTS * D_);
    float4* Og = (float4*)(out + (size_t)bh * N_ * D_ + (size_t)cb * FTS * D_);
    #pragma unroll
    for (int i = 0; i < 4; ++i) {
        int id = i * 512 + t;
        float s = cs[id >> 4];
        float4 vv = Vg[id];
        float4 o; o.x = vv.x * s; o.y = vv.y * s; o.z = vv.z * s; o.w = vv.w * s;
        Og[id] = o;
    }
}

// ---------------------------------------------------------------------------
extern "C" void kernel_launch(void* const* d_in, const int* in_sizes, int n_in,
                              void* d_out, int out_size, void* d_ws, size_t ws_size,
                              hipStream_t stream)
{
    const float* q = (const float*)d_in[0];
    const float* k = (const float*)d_in[1];
    const float* v = (const float*)d_in[2];
    float* out = (float*)d_out;

    const size_t qkBytes = (size_t)2 * BH_ * BHB;          // 32 MB
    const size_t need = qkBytes + (size_t)BH_ * N_ * 4;    // + rinv 512 KB

    if (ws_size >= need) {
        char* qk = (char*)d_ws;
        float* rinv = (float*)(qk + qkBytes);
        mha_convert<<<dim3(2 * BH_ * N_ * 8 / 512), dim3(512), 0, stream>>>(q, k, qk);
        mha_rowsum5<<<dim3(BH_ * 8), dim3(256), 0, stream>>>(qk, rinv);
        mha_colsum5<<<dim3(BH_ * 8), dim3(256), 0, stream>>>(qk, rinv, v, out);
    } else {
        float* rinv = (float*)d_ws;
        mha_rowsum_fb<<<dim3(BH_ * FNT), dim3(512), 0, stream>>>(q, k, rinv);
        mha_colsum_fb<<<dim3(BH_ * FNT), dim3(512), 0, stream>>>(q, k, v, rinv, out);
    }
}

// Round 11
// 108.559 us; speedup vs baseline: 1.9372x; 1.9372x over previous
//
#include <hip/hip_runtime.h>
#include <cstdint>
#include <cstddef>

// [B,H,N,Dh] = [4,16,2048,64]; out[b,h,m,d] = (sum_n softmax(QK^T)[n,m]) * v[b,h,m,d]
#define B_    4
#define H_    16
#define N_    2048
#define D_    64
#define BH_   (B_*H_)
#define SCALE 0.125f
#define QSCL  0.18033688011f      // SCALE * log2(e)

#define P_    256                 // fixed panel (rows pass1 / cols pass2) per wg
#define T_    128                 // streamed tile rows
#define NT    (N_/T_)             // 16
#define NP    (N_/P_)             // 8
#define TILEB 16384               // bytes per bf16 tile: 128 rows x 128 B
#define BHB   (NT*TILEB)          // 256 KB per (bh, tensor)

typedef __attribute__((ext_vector_type(8))) short bf16x8;
typedef __attribute__((ext_vector_type(4))) float f32x4;

#if __has_builtin(__builtin_amdgcn_exp2f)
#define EXP2(x) __builtin_amdgcn_exp2f(x)
#else
#define EXP2(x) exp2f(x)
#endif

#define BARRIER() do { asm volatile("" ::: "memory"); \
                       __builtin_amdgcn_s_barrier();  \
                       asm volatile("" ::: "memory"); } while (0)

__device__ __forceinline__ short f2bf(float f) {
    union { float f; unsigned u; } x; x.f = f;
    unsigned r = x.u + 0x7FFF + ((x.u >> 16) & 1);  // RNE
    return (short)(r >> 16);
}

// byte offset of chunk (row, cc) inside a (bh, tensor) panel; XOR-swizzled so
// 16-row-stride ds_read_b128 is bank-conflict-free (G4)
__device__ __forceinline__ size_t swz(int row, int cc) {
    return ((size_t)(row >> 7) * TILEB) + ((row & 127) << 7) + ((cc ^ (row & 7)) << 4);
}

// async global->LDS copies (HW dest = readfirstlane(addr) + lane*width)
__device__ __forceinline__ void gload_lds16(const char* g, char* l) {
    __builtin_amdgcn_global_load_lds(
        (const __attribute__((address_space(1))) void*)g,
        (__attribute__((address_space(3))) void*)l, 16, 0, 0);
}
__device__ __forceinline__ void gload_lds4(const float* g, float* l) {
    __builtin_amdgcn_global_load_lds(
        (const __attribute__((address_space(1))) void*)g,
        (__attribute__((address_space(3))) void*)l, 4, 0, 0);
}

// ---------------------------------------------------------------------------
// Pre-pass: qk[] = [ Q' (bf16, x QSCL, swizzled image) | K' (bf16, swizzled) ]
// ---------------------------------------------------------------------------
__global__ __launch_bounds__(512)
void mha_convert(const float* __restrict__ q, const float* __restrict__ k,
                 char* __restrict__ qk)
{
    const int gid = blockIdx.x * 512 + threadIdx.x;     // 2*64*16384 chunks
    const int half = BH_ * N_ * 8;
    const bool isq = gid < half;
    const float* src = isq ? q : k;
    const float scl = isq ? QSCL : 1.0f;
    char* dst = qk + (isq ? 0 : (size_t)BH_ * BHB);
    const int id = isq ? gid : gid - half;
    const int bh  = id >> 14;            // 16384 chunks per bh
    const int row = (id >> 3) & 2047;
    const int cc  = id & 7;
    const float* p = src + ((size_t)bh * N_ + row) * D_ + cc * 8;
    float4 a = *(const float4*)p;
    float4 b = *(const float4*)(p + 4);
    bf16x8 o;
    o[0] = f2bf(a.x * scl); o[1] = f2bf(a.y * scl);
    o[2] = f2bf(a.z * scl); o[3] = f2bf(a.w * scl);
    o[4] = f2bf(b.x * scl); o[5] = f2bf(b.y * scl);
    o[6] = f2bf(b.z * scl); o[7] = f2bf(b.w * scl);
    *(bf16x8*)(dst + (size_t)bh * BHB + swz(row, cc)) = o;
}

// ---------------------------------------------------------------------------
// Pass 1: rinv[bh,n] = 1 / sum_m 2^(q'_n . k'_m)
// wg = (bh, 256-row panel); 8 waves x 32 rows (rg=2). K' streamed via
// counted-vmcnt double-buffered global_load_lds: NO vmcnt(0) drain in loop.
// ---------------------------------------------------------------------------
__global__ __launch_bounds__(512)
void mha_rowsum6(const char* __restrict__ qk, float* __restrict__ rinv)
{
    __shared__ __align__(16) char KT[2][TILEB];

    const int t = threadIdx.x, w = t >> 6, l = t & 63;
    const int wid = (blockIdx.x & 7) * 64 + (blockIdx.x >> 3);  // XCD swizzle (512%8==0)
    const int bh = wid / NP, rb = wid % NP;

    const char* Qp = qk + (size_t)bh * BHB;
    const char* Kp = qk + (size_t)BH_ * BHB + (size_t)bh * BHB;

    // Fixed A frags: rows rb*256 + w*32 + rg*16 + (l&15); chunks kh*4+(l>>4)
    bf16x8 af[2][2];
    #pragma unroll
    for (int rg = 0; rg < 2; ++rg)
        #pragma unroll
        for (int kh = 0; kh < 2; ++kh)
            af[rg][kh] = *(const bf16x8*)(Qp + swz(rb * P_ + w * 32 + rg * 16 + (l & 15),
                                                   kh * 4 + (l >> 4)));
    // Pin af now: forces the compiler's vmcnt wait HERE (pre-loop), not in-loop.
    #pragma unroll
    for (int rg = 0; rg < 2; ++rg)
        #pragma unroll
        for (int kh = 0; kh < 2; ++kh)
            asm volatile("" :: "v"(af[rg][kh]));

    // Lane-constant LDS read bases (streamed row = cj*16 + (l&15); row&7=l&7)
    const int lb0 = (l & 15) * 128 + (((l >> 4) ^ (l & 7)) << 4);
    const int lb1 = (l & 15) * 128 + (((4 + (l >> 4)) ^ (l & 7)) << 4);
    const int t16 = t * 16;

    float rs[2][4] = {};

    auto STAGE = [&](int ct, int buf) {             // 2 VMEM instrs per wave
        const char* src = Kp + (size_t)ct * TILEB;
        gload_lds16(src + t16,        KT[buf] + t16);
        gload_lds16(src + 8192 + t16, KT[buf] + 8192 + t16);
    };
    auto COMPUTE = [&](const char* kt) {
        #pragma unroll
        for (int cj = 0; cj < 8; ++cj) {
            bf16x8 b0 = *(const bf16x8*)(kt + lb0 + cj * 2048);
            bf16x8 b1 = *(const bf16x8*)(kt + lb1 + cj * 2048);
            #pragma unroll
            for (int rg = 0; rg < 2; ++rg) {
                f32x4 c = {0.f, 0.f, 0.f, 0.f};
                c = __builtin_amdgcn_mfma_f32_16x16x32_bf16(af[rg][0], b0, c, 0, 0, 0);
                c = __builtin_amdgcn_mfma_f32_16x16x32_bf16(af[rg][1], b1, c, 0, 0, 0);
                rs[rg][0] += EXP2(c[0]);
                rs[rg][1] += EXP2(c[1]);
                rs[rg][2] += EXP2(c[2]);
                rs[rg][3] += EXP2(c[3]);
            }
        }
    };

    STAGE(0, 0);
    STAGE(1, 1);
    #pragma unroll 1
    for (int ct = 0; ct < NT - 2; ++ct) {
        asm volatile("s_waitcnt vmcnt(2)" ::: "memory");   // my tile-ct loads done
        BARRIER();                                         // everyone's done
        COMPUTE(KT[ct & 1]);
        BARRIER();                                         // all reads of buf done
        STAGE(ct + 2, ct & 1);                             // overwrite freed buf
    }
    asm volatile("s_waitcnt vmcnt(2)" ::: "memory");
    BARRIER();
    COMPUTE(KT[(NT - 2) & 1]);
    asm volatile("s_waitcnt vmcnt(0)" ::: "memory");
    BARRIER();
    COMPUTE(KT[(NT - 1) & 1]);

    // Reduce across the 16 col-lanes (l&15); S-row = rg*16 + (l>>4)*4 + i.
    #pragma unroll
    for (int rg = 0; rg < 2; ++rg)
        #pragma unroll
        for (int i = 0; i < 4; ++i) {
            rs[rg][i] += __shfl_xor(rs[rg][i], 1);
            rs[rg][i] += __shfl_xor(rs[rg][i], 2);
            rs[rg][i] += __shfl_xor(rs[rg][i], 4);
            rs[rg][i] += __shfl_xor(rs[rg][i], 8);
        }
    if ((l & 15) == 0) {
        #pragma unroll
        for (int rg = 0; rg < 2; ++rg) {
            const int rbase = rb * P_ + w * 32 + rg * 16 + (l >> 4) * 4;
            #pragma unroll
            for (int i = 0; i < 4; ++i)
                rinv[(size_t)bh * N_ + rbase + i] = 1.0f / rs[rg][i];
        }
    }
}

// ---------------------------------------------------------------------------
// Pass 2: colsum[m] = sum_n 2^(q'_n . k'_m) * rinv[n]; out = colsum[m]*v[m,:]
// wg = (bh, 256-col panel); Q' + rinv streamed via counted-vmcnt pipeline.
// Every wave issues exactly 4 VMEM instrs per STAGE (2 tile + 2 rv).
// ---------------------------------------------------------------------------
__global__ __launch_bounds__(512)
void mha_colsum6(const char* __restrict__ qk, const float* __restrict__ rinv,
                 const float* __restrict__ v, float* __restrict__ out)
{
    __shared__ __align__(16) char QT[2][TILEB];
    __shared__ float rvw[2][8][T_];     // per-wave rinv tile copies (8 KB)
    __shared__ float cs[P_];

    const int t = threadIdx.x, w = t >> 6, l = t & 63;
    const int wid = (blockIdx.x & 7) * 64 + (blockIdx.x >> 3);
    const int bh = wid / NP, cb = wid % NP;

    const char* Qp = qk + (size_t)bh * BHB;
    const char* Kp = qk + (size_t)BH_ * BHB + (size_t)bh * BHB;
    const float* Rg = rinv + (size_t)bh * N_;

    // Fixed B frags: cols cb*256 + w*32 + rg*16 + (l&15)
    bf16x8 kf[2][2];
    #pragma unroll
    for (int rg = 0; rg < 2; ++rg)
        #pragma unroll
        for (int kh = 0; kh < 2; ++kh)
            kf[rg][kh] = *(const bf16x8*)(Kp + swz(cb * P_ + w * 32 + rg * 16 + (l & 15),
                                                    kh * 4 + (l >> 4)));
    #pragma unroll
    for (int rg = 0; rg < 2; ++rg)
        #pragma unroll
        for (int kh = 0; kh < 2; ++kh)
            asm volatile("" :: "v"(kf[rg][kh]));

    const int lb0 = (l & 15) * 128 + (((l >> 4) ^ (l & 7)) << 4);
    const int lb1 = (l & 15) * 128 + (((4 + (l >> 4)) ^ (l & 7)) << 4);
    const int t16 = t * 16;

    float ca[2] = {0.f, 0.f};

    auto STAGE = [&](int rt, int buf) {             // 4 VMEM instrs per wave
        const char* src = Qp + (size_t)rt * TILEB;
        gload_lds16(src + t16,        QT[buf] + t16);
        gload_lds16(src + 8192 + t16, QT[buf] + 8192 + t16);
        const float* rsrc = Rg + rt * T_;
        float* rdst = &rvw[buf][w][0];
        gload_lds4(rsrc + l,      rdst + l);        // base+lane*4 per wave
        gload_lds4(rsrc + 64 + l, rdst + 64 + l);
    };
    auto COMPUTE = [&](const char* qt, const float* rvb) {
        #pragma unroll
        for (int rj = 0; rj < 8; ++rj) {
            bf16x8 a0 = *(const bf16x8*)(qt + lb0 + rj * 2048);
            bf16x8 a1 = *(const bf16x8*)(qt + lb1 + rj * 2048);
            float4 r4 = *(const float4*)(rvb + rj * 16 + (l >> 4) * 4);
            #pragma unroll
            for (int rg = 0; rg < 2; ++rg) {
                f32x4 c = {0.f, 0.f, 0.f, 0.f};
                c = __builtin_amdgcn_mfma_f32_16x16x32_bf16(a0, kf[rg][0], c, 0, 0, 0);
                c = __builtin_amdgcn_mfma_f32_16x16x32_bf16(a1, kf[rg][1], c, 0, 0, 0);
                ca[rg] += EXP2(c[0]) * r4.x + EXP2(c[1]) * r4.y
                        + EXP2(c[2]) * r4.z + EXP2(c[3]) * r4.w;
            }
        }
    };

    STAGE(0, 0);
    STAGE(1, 1);
    #pragma unroll 1
    for (int rt = 0; rt < NT - 2; ++rt) {
        asm volatile("s_waitcnt vmcnt(4)" ::: "memory");
        BARRIER();
        COMPUTE(QT[rt & 1], &rvw[rt & 1][w][0]);
        BARRIER();
        STAGE(rt + 2, rt & 1);
    }
    asm volatile("s_waitcnt vmcnt(4)" ::: "memory");
    BARRIER();
    COMPUTE(QT[(NT - 2) & 1], &rvw[(NT - 2) & 1][w][0]);
    asm volatile("s_waitcnt vmcnt(0)" ::: "memory");
    BARRIER();
    COMPUTE(QT[(NT - 1) & 1], &rvw[(NT - 1) & 1][w][0]);

    // Butterfly across the 4 row-groups -> lanes 0..15 hold colsum
    #pragma unroll
    for (int rg = 0; rg < 2; ++rg) {
        ca[rg] += __shfl_xor(ca[rg], 16);
        ca[rg] += __shfl_xor(ca[rg], 32);
    }
    if (l < 16) { cs[w * 32 + l] = ca[0]; cs[w * 32 + 16 + l] = ca[1]; }
    __syncthreads();

    // out[m][d] = colsum[m] * v[m][d]  (256 rows x 64 d, float4-vectorized)
    const float4* Vg = (const float4*)(v + ((size_t)bh * N_ + cb * P_) * D_);
    float4* Og = (float4*)(out + ((size_t)bh * N_ + cb * P_) * D_);
    #pragma unroll
    for (int i = 0; i < 8; ++i) {
        int id = i * 512 + t;                // 4096 float4 units
        float s = cs[id >> 4];
        float4 vv = Vg[id];
        float4 o; o.x = vv.x * s; o.y = vv.y * s; o.z = vv.z * s; o.w = vv.w * s;
        Og[id] = o;
    }
}

// ===========================================================================
// Fallback (R2 path) if ws_size is too small for the bf16 staging buffers.
// ===========================================================================
#define FTS 128
#define FNT 16

__device__ __forceinline__ bf16x8 cvt8(const float* p) {
    float4 a = *(const float4*)p;
    float4 b = *(const float4*)(p + 4);
    bf16x8 r;
    r[0] = f2bf(a.x); r[1] = f2bf(a.y); r[2] = f2bf(a.z); r[3] = f2bf(a.w);
    r[4] = f2bf(b.x); r[5] = f2bf(b.y); r[6] = f2bf(b.z); r[7] = f2bf(b.w);
    return r;
}
__device__ __forceinline__ void fstage(char* lds, const float* src, int t) {
    #pragma unroll
    for (int i = 0; i < 2; ++i) {
        int ch = i * 512 + t, r = ch >> 3, cc = ch & 7;
        bf16x8 v = cvt8(src + (size_t)r * D_ + cc * 8);
        *(bf16x8*)(lds + r * 128 + ((cc ^ (r & 7)) << 4)) = v;
    }
}
__device__ __forceinline__ bf16x8 fread(const char* lds, int row, int cc) {
    return *(const bf16x8*)(lds + row * 128 + ((cc ^ (row & 7)) << 4));
}

__global__ __launch_bounds__(512)
void mha_rowsum_fb(const float* __restrict__ q, const float* __restrict__ k,
                   float* __restrict__ rinv)
{
    __shared__ __align__(16) char KT[FTS * 128];
    const int t = threadIdx.x, w = t >> 6, l = t & 63;
    const int bh = blockIdx.x / FNT, rb = blockIdx.x % FNT;
    const float* Qg = q + (size_t)bh * N_ * D_;
    const float* Kg = k + (size_t)bh * N_ * D_;
    const int qrow = rb * FTS + w * 16 + (l & 15);
    bf16x8 af[2];
    #pragma unroll
    for (int kh = 0; kh < 2; ++kh)
        af[kh] = cvt8(Qg + (size_t)qrow * D_ + kh * 32 + (l >> 4) * 8);
    float rs[4] = {0.f, 0.f, 0.f, 0.f};
    for (int ct = 0; ct < FNT; ++ct) {
        __syncthreads();
        fstage(KT, Kg + (size_t)ct * FTS * D_, t);
        __syncthreads();
        #pragma unroll
        for (int cj = 0; cj < 8; ++cj) {
            const int krow = cj * 16 + (l & 15);
            f32x4 c = {0.f, 0.f, 0.f, 0.f};
            #pragma unroll
            for (int kh = 0; kh < 2; ++kh)
                c = __builtin_amdgcn_mfma_f32_16x16x32_bf16(af[kh], fread(KT, krow, kh * 4 + (l >> 4)), c, 0, 0, 0);
            rs[0] += __expf(c[0] * SCALE); rs[1] += __expf(c[1] * SCALE);
            rs[2] += __expf(c[2] * SCALE); rs[3] += __expf(c[3] * SCALE);
        }
    }
    #pragma unroll
    for (int i = 0; i < 4; ++i) {
        rs[i] += __shfl_xor(rs[i], 1); rs[i] += __shfl_xor(rs[i], 2);
        rs[i] += __shfl_xor(rs[i], 4); rs[i] += __shfl_xor(rs[i], 8);
    }
    if ((l & 15) == 0) {
        const int rbase = rb * FTS + w * 16 + (l >> 4) * 4;
        #pragma unroll
        for (int i = 0; i < 4; ++i)
            rinv[(size_t)bh * N_ + rbase + i] = 1.0f / rs[i];
    }
}

__global__ __launch_bounds__(512)
void mha_colsum_fb(const float* __restrict__ q, const float* __restrict__ k,
                   const float* __restrict__ v, const float* __restrict__ rinv,
                   float* __restrict__ out)
{
    __shared__ __align__(16) char QT[FTS * 128];
    __shared__ float rv[FTS];
    __shared__ float cs[FTS];
    const int t = threadIdx.x, w = t >> 6, l = t & 63;
    const int bh = blockIdx.x / FNT, cb = blockIdx.x % FNT;
    const float* Qg = q + (size_t)bh * N_ * D_;
    const float* Kg = k + (size_t)bh * N_ * D_;
    const float* Rg = rinv + (size_t)bh * N_;
    const int kcol = cb * FTS + w * 16 + (l & 15);
    bf16x8 kf[2];
    #pragma unroll
    for (int kh = 0; kh < 2; ++kh)
        kf[kh] = cvt8(Kg + (size_t)kcol * D_ + kh * 32 + (l >> 4) * 8);
    float ca = 0.f;
    for (int rt = 0; rt < FNT; ++rt) {
        __syncthreads();
        fstage(QT, Qg + (size_t)rt * FTS * D_, t);
        if (t < FTS) rv[t] = Rg[rt * FTS + t];
        __syncthreads();
        #pragma unroll
        for (int rj = 0; rj < 8; ++rj) {
            const int qr = rj * 16 + (l & 15);
            f32x4 c = {0.f, 0.f, 0.f, 0.f};
            #pragma unroll
            for (int kh = 0; kh < 2; ++kh)
                c = __builtin_amdgcn_mfma_f32_16x16x32_bf16(fread(QT, qr, kh * 4 + (l >> 4)), kf[kh], c, 0, 0, 0);
            float4 r4 = *(const float4*)&rv[rj * 16 + (l >> 4) * 4];
            ca += __expf(c[0] * SCALE) * r4.x + __expf(c[1] * SCALE) * r4.y
                + __expf(c[2] * SCALE) * r4.z + __expf(c[3] * SCALE) * r4.w;
        }
    }
    ca += __shfl_xor(ca, 16); ca += __shfl_xor(ca, 32);
    if (l < 16) cs[w * 16 + l] = ca;
    __syncthreads();
    const float4* Vg = (const float4*)(v + (size_t)bh * N_ * D_ + (size_t)cb * FTS * D_);
    float4* Og = (float4*)(out + (size_t)bh * N_ * D_ + (size_t)cb * FTS * D_);
    #pragma unroll
    for (int i = 0; i < 4; ++i) {
        int id = i * 512 + t;
        float s = cs[id >> 4];
        float4 vv = Vg[id];
        float4 o; o.x = vv.x * s; o.y = vv.y * s; o.z = vv.z * s; o.w = vv.w * s;
        Og[id] = o;
    }
}

// ---------------------------------------------------------------------------
extern "C" void kernel_launch(void* const* d_in, const int* in_sizes, int n_in,
                              void* d_out, int out_size, void* d_ws, size_t ws_size,
                              hipStream_t stream)
{
    const float* q = (const float*)d_in[0];
    const float* k = (const float*)d_in[1];
    const float* v = (const float*)d_in[2];
    float* out = (float*)d_out;

    const size_t qkBytes = (size_t)2 * BH_ * BHB;          // 32 MB
    const size_t need = qkBytes + (size_t)BH_ * N_ * 4;    // + rinv 512 KB

    if (ws_size >= need) {
        char* qk = (char*)d_ws;
        float* rinv = (float*)(qk + qkBytes);
        mha_convert<<<dim3(2 * BH_ * N_ * 8 / 512), dim3(512), 0, stream>>>(q, k, qk);
        mha_rowsum6<<<dim3(BH_ * NP), dim3(512), 0, stream>>>(qk, rinv);
        mha_colsum6<<<dim3(BH_ * NP), dim3(512), 0, stream>>>(qk, rinv, v, out);
    } else {
        float* rinv = (float*)d_ws;
        mha_rowsum_fb<<<dim3(BH_ * FNT), dim3(512), 0, stream>>>(q, k, rinv);
        mha_colsum_fb<<<dim3(BH_ * FNT), dim3(512), 0, stream>>>(q, k, v, rinv, out);
    }
}